// Round 3
// baseline (183.545 us; speedup 1.0000x reference)
//
#include <hip/hip_runtime.h>
#include <cmath>

#define HDIM 1024
#define LSEQ 2048
#define VOCAB 50257
#define LOGIT_BLOCKS ((VOCAB + 3) / 4)   // 12565

__device__ __forceinline__ float wave_sum(float v) {
#pragma unroll
    for (int off = 32; off; off >>= 1) v += __shfl_down(v, off, 64);
    return v;
}

__device__ __forceinline__ void lse_combine(float& m, float& s, float m2, float s2) {
    float nm = fmaxf(m, m2);
    s = s * expf(m - nm) + s2 * expf(m2 - nm);
    m = nm;
}

// ---------------------------------------------------------------------------
// 1. h = tanh(W_ih @ x + b_ih + W_hh @ h0 + b_hh);  one wave per output row.
__global__ void rnn_kernel(const int* __restrict__ tok,
                           const float* __restrict__ hidden,
                           const float* __restrict__ emb,
                           const float* __restrict__ W_ih,
                           const float* __restrict__ W_hh,
                           const float* __restrict__ b_ih,
                           const float* __restrict__ b_hh,
                           float* __restrict__ concat,
                           float* __restrict__ out_h) {
    int wave = threadIdx.x >> 6, lane = threadIdx.x & 63;
    int row = blockIdx.x * 4 + wave;            // 512 blocks * 4 waves = 2048
    int d = row >> 10, i = row & 1023;
    int t = tok[0];
    const float* x  = emb + (size_t)t * HDIM;
    const float* h0 = hidden + d * HDIM;
    const float* wi = W_ih + (size_t)d * HDIM * HDIM + (size_t)i * HDIM;
    const float* wh = W_hh + (size_t)d * HDIM * HDIM + (size_t)i * HDIM;
    float acc = 0.f;
#pragma unroll
    for (int p = 0; p < 4; ++p) {
        int o = p * 256 + lane * 4;
        float4 a = *(const float4*)(wi + o);
        float4 b = *(const float4*)(x + o);
        acc += a.x * b.x + a.y * b.y + a.z * b.z + a.w * b.w;
        float4 c = *(const float4*)(wh + o);
        float4 e = *(const float4*)(h0 + o);
        acc += c.x * e.x + c.y * e.y + c.z * e.z + c.w * e.w;
    }
    acc = wave_sum(acc);
    if (lane == 0) {
        float hv = tanhf(acc + b_ih[d * HDIM + i] + b_hh[d * HDIM + i]);
        concat[d * 2048 + 1024 + i] = hv;
        out_h[d * HDIM + i] = hv;
    }
}

// ---------------------------------------------------------------------------
// 2. Flash-style fused attention partials.
//    128 blocks: d = b>>6, chunk c = b&63 covering 32 enc rows.
//    Phase A: energies e_l = h[d].enc[l] (4 waves x 8 rows).
//    Phase B: local max/sum + weighted partial accumulation (enc L2-hot).
__global__ void flash_attn_kernel(const float* __restrict__ enc,
                                  const float* __restrict__ concat,
                                  float* __restrict__ part,
                                  float* __restrict__ pm_a,
                                  float* __restrict__ ps_a) {
    __shared__ float e_sh[32];
    int b = blockIdx.x;
    int d = b >> 6, c = b & 63;
    int t = threadIdx.x, wave = t >> 6, lane = t & 63;
    int base = c * 32;
    const float* h = concat + d * 2048 + 1024;

    // Phase A: each wave computes 8 energies
    for (int r = 0; r < 8; ++r) {
        int ll = wave * 8 + r;
        const float* er = enc + (size_t)(base + ll) * HDIM;
        float acc = 0.f;
#pragma unroll
        for (int p = 0; p < 4; ++p) {
            int o = p * 256 + lane * 4;
            float4 a = *(const float4*)(er + o);
            float4 bb = *(const float4*)(h + o);
            acc += a.x * bb.x + a.y * bb.y + a.z * bb.z + a.w * bb.w;
        }
        acc = wave_sum(acc);
        if (lane == 0) e_sh[ll] = acc;
    }
    __syncthreads();

    // Phase B: redundant per-thread local max, then weighted accumulation
    float m_c = -1e30f;
#pragma unroll
    for (int l = 0; l < 32; ++l) m_c = fmaxf(m_c, e_sh[l]);
    float s_c = 0.f;
    float acc0 = 0, acc1 = 0, acc2 = 0, acc3 = 0;
    for (int l = 0; l < 32; ++l) {
        float p = expf(e_sh[l] - m_c);
        s_c += p;
        const float* row = enc + (size_t)(base + l) * HDIM;
        acc0 += p * row[t];
        acc1 += p * row[t + 256];
        acc2 += p * row[t + 512];
        acc3 += p * row[t + 768];
    }
    float* pp = part + (size_t)b * HDIM;
    pp[t] = acc0; pp[t + 256] = acc1; pp[t + 512] = acc2; pp[t + 768] = acc3;
    if (t == 0) { pm_a[b] = m_c; ps_a[b] = s_c; }
}

// ---------------------------------------------------------------------------
// 3. Combine 64 chunks per direction with rescaling -> concat attn slots.
//    8 blocks x 256 -> idx 0..2047;  d = idx>>10, h = idx&1023.
__global__ void attn_combine_kernel(const float* __restrict__ part,
                                    const float* __restrict__ pm_a,
                                    const float* __restrict__ ps_a,
                                    float* __restrict__ concat) {
    int idx = blockIdx.x * 256 + threadIdx.x;
    int d = idx >> 10, h = idx & 1023;
    // global max over this direction's 64 chunks
    float M = -1e30f;
    for (int c = 0; c < 64; ++c) M = fmaxf(M, pm_a[d * 64 + c]);
    float S = 0.f, acc = 0.f;
    for (int c = 0; c < 64; ++c) {
        int cb = d * 64 + c;
        float w = expf(pm_a[cb] - M);
        S += ps_a[cb] * w;
        acc += part[(size_t)cb * HDIM + h] * w;
    }
    concat[d * 2048 + h] = acc / S;
}

// ---------------------------------------------------------------------------
// 4. logits[v] = concat . W_out[v] + b_out[v], one wave per row,
//    plus fused per-block LSE partial over this block's 4 logits.
__global__ void logits_kernel(const float* __restrict__ W_out,
                              const float* __restrict__ b_out,
                              const float* __restrict__ concat,
                              float* __restrict__ logits,
                              float* __restrict__ pm,
                              float* __restrict__ ps) {
    __shared__ float lv[4];
    int wave = threadIdx.x >> 6, lane = threadIdx.x & 63;
    int v = blockIdx.x * 4 + wave;
    bool valid = v < VOCAB;
    int vc = valid ? v : (VOCAB - 1);
    const float* w = W_out + (size_t)vc * 4096;
    float acc = 0.f;
#pragma unroll
    for (int p = 0; p < 16; ++p) {
        int o = p * 256 + lane * 4;
        float4 a = *(const float4*)(w + o);
        float4 b = *(const float4*)(concat + o);
        acc += a.x * b.x + a.y * b.y + a.z * b.z + a.w * b.w;
    }
    acc = wave_sum(acc);
    if (lane == 0) {
        float val = acc + b_out[vc];
        if (valid) logits[v] = val;
        lv[wave] = valid ? val : -1e30f;
    }
    __syncthreads();
    if (threadIdx.x == 0) {
        float m = fmaxf(fmaxf(lv[0], lv[1]), fmaxf(lv[2], lv[3]));
        float s = 0.f;
#pragma unroll
        for (int k = 0; k < 4; ++k)
            if (lv[k] > -1e29f) s += expf(lv[k] - m);
        pm[blockIdx.x] = m;
        ps[blockIdx.x] = s;
    }
}

// ---------------------------------------------------------------------------
// 5. out[v] = logits[v] - M.  Each block redundantly reduces the 12565
//    (m,s) partials (L2-hot, ~100 KB) -> deterministic, no extra kernel.
__global__ void out_kernel(const float* __restrict__ logits,
                           const float* __restrict__ pm,
                           const float* __restrict__ ps,
                           float* __restrict__ out) {
    __shared__ float rm[4], rs[4], Msh;
    int t = threadIdx.x, lane = t & 63, wave = t >> 6;
    float m = -1e30f, s = 0.f;
    for (int i = t; i < LOGIT_BLOCKS; i += 256) lse_combine(m, s, pm[i], ps[i]);
#pragma unroll
    for (int off = 32; off; off >>= 1) {
        float m2 = __shfl_down(m, off, 64);
        float s2 = __shfl_down(s, off, 64);
        lse_combine(m, s, m2, s2);
    }
    if (lane == 0) { rm[wave] = m; rs[wave] = s; }
    __syncthreads();
    if (t == 0) {
        float fm = rm[0], fs = rs[0];
        for (int k = 1; k < 4; ++k) lse_combine(fm, fs, rm[k], rs[k]);
        Msh = fm + logf(fs);
    }
    __syncthreads();
    float M = Msh;
    int v = blockIdx.x * 256 + t;
    if (v < VOCAB) out[v] = logits[v] - M;
}

// ---------------------------------------------------------------------------
extern "C" void kernel_launch(void* const* d_in, const int* in_sizes, int n_in,
                              void* d_out, int out_size, void* d_ws, size_t ws_size,
                              hipStream_t stream) {
    const int*   tok    = (const int*)d_in[0];
    const float* hidden = (const float*)d_in[1];
    const float* enc    = (const float*)d_in[2];
    const float* emb    = (const float*)d_in[3];
    const float* W_ih   = (const float*)d_in[4];
    const float* W_hh   = (const float*)d_in[5];
    const float* b_ih   = (const float*)d_in[6];
    const float* b_hh   = (const float*)d_in[7];
    const float* W_out  = (const float*)d_in[8];
    const float* b_out  = (const float*)d_in[9];
    float* out = (float*)d_out;

    float* ws     = (float*)d_ws;
    float* concat = ws;                  // 4096
    float* pm_a   = ws + 4096;           // 128
    float* ps_a   = ws + 4224;           // 128
    float* pm     = ws + 4352;           // 12576 (pad)
    float* ps     = ws + 16928;          // 12576
    float* part   = ws + 29504;          // 128*1024 = 131072
    float* logits = ws + 29504;          // aliases part (part dead before K4)
    // total footprint: 29504 + 131072 = 160576 floats ≈ 642 KB

    rnn_kernel<<<512, 256, 0, stream>>>(tok, hidden, emb, W_ih, W_hh, b_ih, b_hh,
                                        concat, out + VOCAB);
    flash_attn_kernel<<<128, 256, 0, stream>>>(enc, concat, part, pm_a, ps_a);
    attn_combine_kernel<<<8, 256, 0, stream>>>(part, pm_a, ps_a, concat);
    logits_kernel<<<LOGIT_BLOCKS, 256, 0, stream>>>(W_out, b_out, concat, logits, pm, ps);
    out_kernel<<<(VOCAB + 255) / 256, 256, 0, stream>>>(logits, pm, ps, out);
}

// Round 4
// 160.724 us; speedup vs baseline: 1.1420x; 1.1420x over previous
//
#include <hip/hip_runtime.h>
#include <cmath>

#define HDIM 1024
#define LSEQ 2048
#define VOCAB 50257

__device__ __forceinline__ float wave_sum(float v) {
#pragma unroll
    for (int off = 32; off; off >>= 1) v += __shfl_down(v, off, 64);
    return v;
}

__device__ __forceinline__ float wave_max(float v) {
#pragma unroll
    for (int off = 32; off; off >>= 1) v = fmaxf(v, __shfl_down(v, off, 64));
    return v;
}

__device__ __forceinline__ void lse_combine(float& m, float& s, float m2, float s2) {
    float nm = fmaxf(m, m2);
    s = s * expf(m - nm) + s2 * expf(m2 - nm);
    m = nm;
}

// ---------------------------------------------------------------------------
// 1. h = tanh(W_ih @ x + b_ih + W_hh @ h0 + b_hh);  one wave per output row.
__global__ void rnn_kernel(const int* __restrict__ tok,
                           const float* __restrict__ hidden,
                           const float* __restrict__ emb,
                           const float* __restrict__ W_ih,
                           const float* __restrict__ W_hh,
                           const float* __restrict__ b_ih,
                           const float* __restrict__ b_hh,
                           float* __restrict__ concat,
                           float* __restrict__ out_h) {
    int wave = threadIdx.x >> 6, lane = threadIdx.x & 63;
    int row = blockIdx.x * 4 + wave;            // 512 blocks * 4 waves = 2048
    int d = row >> 10, i = row & 1023;
    int t = tok[0];
    const float* x  = emb + (size_t)t * HDIM;
    const float* h0 = hidden + d * HDIM;
    const float* wi = W_ih + (size_t)d * HDIM * HDIM + (size_t)i * HDIM;
    const float* wh = W_hh + (size_t)d * HDIM * HDIM + (size_t)i * HDIM;
    float acc = 0.f;
#pragma unroll
    for (int p = 0; p < 4; ++p) {
        int o = p * 256 + lane * 4;
        float4 a = *(const float4*)(wi + o);
        float4 b = *(const float4*)(x + o);
        acc += a.x * b.x + a.y * b.y + a.z * b.z + a.w * b.w;
        float4 c = *(const float4*)(wh + o);
        float4 e = *(const float4*)(h0 + o);
        acc += c.x * e.x + c.y * e.y + c.z * e.z + c.w * e.w;
    }
    acc = wave_sum(acc);
    if (lane == 0) {
        float hv = tanhf(acc + b_ih[d * HDIM + i] + b_hh[d * HDIM + i]);
        concat[d * 2048 + 1024 + i] = hv;
        out_h[d * HDIM + i] = hv;
    }
}

// ---------------------------------------------------------------------------
// 2. energy[d][l] = h[d] . enc[l];  one wave per (d,l).  rows 0..4095
__global__ void energy_kernel(const float* __restrict__ enc,
                              const float* __restrict__ concat,
                              float* __restrict__ energy) {
    int wave = threadIdx.x >> 6, lane = threadIdx.x & 63;
    int row = blockIdx.x * 4 + wave;            // 1024 blocks * 4 waves = 4096
    int d = row >> 11, l = row & 2047;
    const float* h  = concat + d * 2048 + 1024;
    const float* er = enc + (size_t)l * HDIM;
    float acc = 0.f;
#pragma unroll
    for (int p = 0; p < 4; ++p) {
        int o = p * 256 + lane * 4;
        float4 a = *(const float4*)(er + o);
        float4 b = *(const float4*)(h + o);
        acc += a.x * b.x + a.y * b.y + a.z * b.z + a.w * b.w;
    }
    acc = wave_sum(acc);
    if (lane == 0) energy[row] = acc;
}

// ---------------------------------------------------------------------------
// 3. attn_out partials with fused (redundant, deterministic) softmax stats.
//    64 blocks: d = b>>5, l-chunk c = b&31 (64 l each).
//    Every block of direction d recomputes the SAME block-reduction over the
//    L2-hot 8 KB energy row -> identical m,s -> deterministic.
__global__ void attnout_partial_kernel(const float* __restrict__ enc,
                                       const float* __restrict__ energy,
                                       float* __restrict__ part) {
    __shared__ float red[4];
    int b = blockIdx.x;                          // 64 blocks
    int d = b >> 5, c = b & 31;
    int t = threadIdx.x, lane = t & 63, wave = t >> 6;
    const float* e = energy + d * LSEQ;

    float ev[8];
    float m = -1e30f;
#pragma unroll
    for (int k = 0; k < 8; ++k) { ev[k] = e[t + 256 * k]; m = fmaxf(m, ev[k]); }
    m = wave_max(m);
    if (lane == 0) red[wave] = m;
    __syncthreads();
    m = fmaxf(fmaxf(red[0], red[1]), fmaxf(red[2], red[3]));
    __syncthreads();
    float s = 0.f;
#pragma unroll
    for (int k = 0; k < 8; ++k) s += expf(ev[k] - m);
    s = wave_sum(s);
    if (lane == 0) red[wave] = s;
    __syncthreads();
    s = red[0] + red[1] + red[2] + red[3];
    float inv = 1.f / s;

    // weighted accumulation over this block's 64 enc rows
    float acc0 = 0, acc1 = 0, acc2 = 0, acc3 = 0;
    const float* ech   = e + c * 64;
    const float* ebase = enc + (size_t)(c * 64) * HDIM;
    for (int l = 0; l < 64; ++l) {
        float p = expf(ech[l] - m) * inv;
        const float* row = ebase + (size_t)l * HDIM;
        acc0 += p * row[t];
        acc1 += p * row[t + 256];
        acc2 += p * row[t + 512];
        acc3 += p * row[t + 768];
    }
    float* pp = part + (size_t)b * HDIM;
    pp[t] = acc0; pp[t + 256] = acc1; pp[t + 512] = acc2; pp[t + 768] = acc3;
}

// 3b. reduce partials over 32 chunks -> concat[d*2048 + h]
__global__ void attnout_reduce_kernel(const float* __restrict__ part,
                                      float* __restrict__ concat) {
    int idx = blockIdx.x * 256 + threadIdx.x;    // 8 blocks -> 0..2047
    int d = idx >> 10, h = idx & 1023;
    float s = 0.f;
#pragma unroll 8
    for (int c = 0; c < 32; ++c) s += part[(size_t)(d * 32 + c) * HDIM + h];
    concat[d * 2048 + h] = s;
}

// ---------------------------------------------------------------------------
// 4. logits[v] = concat . W_out[v] + b_out[v];  one wave per vocab row.
//    BYTE-IDENTICAL to the round-2 version (known 6 TB/s). Do not touch.
__global__ void logits_kernel(const float* __restrict__ W_out,
                              const float* __restrict__ b_out,
                              const float* __restrict__ concat,
                              float* __restrict__ logits) {
    int wave = threadIdx.x >> 6, lane = threadIdx.x & 63;
    int v = blockIdx.x * 4 + wave;
    if (v >= VOCAB) return;
    const float* w = W_out + (size_t)v * 4096;
    float acc = 0.f;
#pragma unroll
    for (int p = 0; p < 16; ++p) {
        int o = p * 256 + lane * 4;
        float4 a = *(const float4*)(w + o);
        float4 b = *(const float4*)(concat + o);
        acc += a.x * b.x + a.y * b.y + a.z * b.z + a.w * b.w;
    }
    acc = wave_sum(acc);
    if (lane == 0) logits[v] = acc + b_out[v];
}

// ---------------------------------------------------------------------------
// 5. per-block online log-sum-exp partials over logits. grid=128, block=256.
__global__ void lse_partial_kernel(const float* __restrict__ logits,
                                   float* __restrict__ pm,
                                   float* __restrict__ ps) {
    __shared__ float rm[4], rs[4];
    int tid = blockIdx.x * 256 + threadIdx.x;
    float m = -1e30f, s = 0.f;
    for (int v = tid; v < VOCAB; v += 128 * 256) lse_combine(m, s, logits[v], 1.f);
    int lane = threadIdx.x & 63, wave = threadIdx.x >> 6;
#pragma unroll
    for (int off = 32; off; off >>= 1) {
        float m2 = __shfl_down(m, off, 64);
        float s2 = __shfl_down(s, off, 64);
        lse_combine(m, s, m2, s2);
    }
    if (lane == 0) { rm[wave] = m; rs[wave] = s; }
    __syncthreads();
    if (threadIdx.x == 0) {
        float fm = rm[0], fs = rs[0];
        for (int w = 1; w < 4; ++w) lse_combine(fm, fs, rm[w], rs[w]);
        pm[blockIdx.x] = fm;
        ps[blockIdx.x] = fs;
    }
}

// ---------------------------------------------------------------------------
// 6. out[v] = logits[v] - M, with M recomputed per block from the 128
//    partials (cheap, deterministic identical order in every block).
__global__ void out_kernel(const float* __restrict__ logits,
                           const float* __restrict__ pm,
                           const float* __restrict__ ps,
                           float* __restrict__ out) {
    __shared__ float rm[2], rs[2], Msh;
    int t = threadIdx.x, lane = t & 63, wave = t >> 6;
    float m = -1e30f, s = 0.f;
    if (t < 128) { m = pm[t]; s = ps[t]; }
#pragma unroll
    for (int off = 32; off; off >>= 1) {
        float m2 = __shfl_down(m, off, 64);
        float s2 = __shfl_down(s, off, 64);
        lse_combine(m, s, m2, s2);
    }
    if (lane == 0 && wave < 2) { rm[wave] = m; rs[wave] = s; }
    __syncthreads();
    if (t == 0) {
        float fm = rm[0], fs = rs[0];
        lse_combine(fm, fs, rm[1], rs[1]);
        Msh = fm + logf(fs);
    }
    __syncthreads();
    float M = Msh;
    int v = blockIdx.x * 256 + t;
    if (v < VOCAB) out[v] = logits[v] - M;
}

// ---------------------------------------------------------------------------
extern "C" void kernel_launch(void* const* d_in, const int* in_sizes, int n_in,
                              void* d_out, int out_size, void* d_ws, size_t ws_size,
                              hipStream_t stream) {
    const int*   tok    = (const int*)d_in[0];
    const float* hidden = (const float*)d_in[1];
    const float* enc    = (const float*)d_in[2];
    const float* emb    = (const float*)d_in[3];
    const float* W_ih   = (const float*)d_in[4];
    const float* W_hh   = (const float*)d_in[5];
    const float* b_ih   = (const float*)d_in[6];
    const float* b_hh   = (const float*)d_in[7];
    const float* W_out  = (const float*)d_in[8];
    const float* b_out  = (const float*)d_in[9];
    float* out = (float*)d_out;

    float* ws     = (float*)d_ws;
    float* concat = ws;              // 4096   [a0 | h0 | a1 | h1]
    float* energy = ws + 4096;       // 4096
    float* pm     = ws + 8192;       // 128
    float* ps     = ws + 8320;       // 128
    float* logits = ws + 8448;       // 50304 (padded)
    float* part   = ws + 58752;      // 64*1024 = 65536

    rnn_kernel<<<512, 256, 0, stream>>>(tok, hidden, emb, W_ih, W_hh, b_ih, b_hh,
                                        concat, out + VOCAB);
    energy_kernel<<<1024, 256, 0, stream>>>(enc, concat, energy);
    attnout_partial_kernel<<<64, 256, 0, stream>>>(enc, energy, part);
    attnout_reduce_kernel<<<8, 256, 0, stream>>>(part, concat);
    logits_kernel<<<(VOCAB + 3) / 4, 256, 0, stream>>>(W_out, b_out, concat, logits);
    lse_partial_kernel<<<128, 256, 0, stream>>>(logits, pm, ps);
    out_kernel<<<(VOCAB + 255) / 256, 256, 0, stream>>>(logits, pm, ps, out);
}

// Round 5
// 154.729 us; speedup vs baseline: 1.1862x; 1.0388x over previous
//
#include <hip/hip_runtime.h>
#include <cmath>

#define HDIM 1024
#define LSEQ 2048
#define VOCAB 50257

typedef float f4 __attribute__((ext_vector_type(4)));

__device__ __forceinline__ float wave_sum(float v) {
#pragma unroll
    for (int off = 32; off; off >>= 1) v += __shfl_down(v, off, 64);
    return v;
}

__device__ __forceinline__ void lse_combine(float& m, float& s, float m2, float s2) {
    float nm = fmaxf(m, m2);
    s = s * expf(m - nm) + s2 * expf(m2 - nm);
    m = nm;
}

// ---------------------------------------------------------------------------
// 1. h = tanh(W_ih @ x + b_ih + W_hh @ h0 + b_hh);  one wave per output row.
__global__ void rnn_kernel(const int* __restrict__ tok,
                           const float* __restrict__ hidden,
                           const float* __restrict__ emb,
                           const float* __restrict__ W_ih,
                           const float* __restrict__ W_hh,
                           const float* __restrict__ b_ih,
                           const float* __restrict__ b_hh,
                           float* __restrict__ concat,
                           float* __restrict__ out_h) {
    int wave = threadIdx.x >> 6, lane = threadIdx.x & 63;
    int row = blockIdx.x * 4 + wave;            // 512 blocks * 4 waves = 2048
    int d = row >> 10, i = row & 1023;
    int t = tok[0];
    const float* x  = emb + (size_t)t * HDIM;
    const float* h0 = hidden + d * HDIM;
    const float* wi = W_ih + (size_t)d * HDIM * HDIM + (size_t)i * HDIM;
    const float* wh = W_hh + (size_t)d * HDIM * HDIM + (size_t)i * HDIM;
    float acc = 0.f;
#pragma unroll
    for (int p = 0; p < 4; ++p) {
        int o = p * 256 + lane * 4;
        float4 a = *(const float4*)(wi + o);
        float4 b = *(const float4*)(x + o);
        acc += a.x * b.x + a.y * b.y + a.z * b.z + a.w * b.w;
        float4 c = *(const float4*)(wh + o);
        float4 e = *(const float4*)(h0 + o);
        acc += c.x * e.x + c.y * e.y + c.z * e.z + c.w * e.w;
    }
    acc = wave_sum(acc);
    if (lane == 0) {
        float hv = tanhf(acc + b_ih[d * HDIM + i] + b_hh[d * HDIM + i]);
        concat[d * 2048 + 1024 + i] = hv;
        out_h[d * HDIM + i] = hv;
    }
}

// ---------------------------------------------------------------------------
// 2. Flash-style fused attention partials (proven in round 3).
//    128 blocks: d = b>>6, chunk c = b&63 covering 32 enc rows.
//    enc read once from HBM (phase A); phase B re-read is L2-hot.
__global__ void flash_attn_kernel(const float* __restrict__ enc,
                                  const float* __restrict__ concat,
                                  float* __restrict__ part,
                                  float* __restrict__ pm_a,
                                  float* __restrict__ ps_a) {
    __shared__ float e_sh[32];
    int b = blockIdx.x;
    int d = b >> 6, c = b & 63;
    int t = threadIdx.x, wave = t >> 6, lane = t & 63;
    int base = c * 32;
    const float* h = concat + d * 2048 + 1024;

    for (int r = 0; r < 8; ++r) {
        int ll = wave * 8 + r;
        const float* er = enc + (size_t)(base + ll) * HDIM;
        float acc = 0.f;
#pragma unroll
        for (int p = 0; p < 4; ++p) {
            int o = p * 256 + lane * 4;
            float4 a = *(const float4*)(er + o);
            float4 bb = *(const float4*)(h + o);
            acc += a.x * bb.x + a.y * bb.y + a.z * bb.z + a.w * bb.w;
        }
        acc = wave_sum(acc);
        if (lane == 0) e_sh[ll] = acc;
    }
    __syncthreads();

    float m_c = -1e30f;
#pragma unroll
    for (int l = 0; l < 32; ++l) m_c = fmaxf(m_c, e_sh[l]);
    float s_c = 0.f;
    float acc0 = 0, acc1 = 0, acc2 = 0, acc3 = 0;
    for (int l = 0; l < 32; ++l) {
        float p = expf(e_sh[l] - m_c);
        s_c += p;
        const float* row = enc + (size_t)(base + l) * HDIM;
        acc0 += p * row[t];
        acc1 += p * row[t + 256];
        acc2 += p * row[t + 512];
        acc3 += p * row[t + 768];
    }
    float* pp = part + (size_t)b * HDIM;
    pp[t] = acc0; pp[t + 256] = acc1; pp[t + 512] = acc2; pp[t + 768] = acc3;
    if (t == 0) { pm_a[b] = m_c; ps_a[b] = s_c; }
}

// ---------------------------------------------------------------------------
// 3. Combine 64 chunks per direction with rescaling -> concat attn slots.
__global__ void attn_combine_kernel(const float* __restrict__ part,
                                    const float* __restrict__ pm_a,
                                    const float* __restrict__ ps_a,
                                    float* __restrict__ concat) {
    int idx = blockIdx.x * 256 + threadIdx.x;   // 8 blocks -> 0..2047
    int d = idx >> 10, h = idx & 1023;
    float M = -1e30f;
    for (int c = 0; c < 64; ++c) M = fmaxf(M, pm_a[d * 64 + c]);
    float S = 0.f, acc = 0.f;
    for (int c = 0; c < 64; ++c) {
        int cb = d * 64 + c;
        float w = expf(pm_a[cb] - M);
        S += ps_a[cb] * w;
        acc += part[(size_t)cb * HDIM + h] * w;
    }
    concat[d * 2048 + h] = acc / S;
}

// ---------------------------------------------------------------------------
// 4. logits[v] = concat . W_out[v] + b_out[v];  one wave per vocab row.
//    W_out read via NON-TEMPORAL loads (zero reuse, 823 MB stream);
//    concat loads stay cached (reused by every block).
__global__ void logits_kernel(const float* __restrict__ W_out,
                              const float* __restrict__ b_out,
                              const float* __restrict__ concat,
                              float* __restrict__ logits) {
    int wave = threadIdx.x >> 6, lane = threadIdx.x & 63;
    int v = blockIdx.x * 4 + wave;
    if (v >= VOCAB) return;
    const float* w = W_out + (size_t)v * 4096;
    float acc = 0.f;
#pragma unroll
    for (int p = 0; p < 16; ++p) {
        int o = p * 256 + lane * 4;
        f4 a = __builtin_nontemporal_load((const f4*)(w + o));
        float4 b = *(const float4*)(concat + o);
        acc += a.x * b.x + a.y * b.y + a.z * b.z + a.w * b.w;
    }
    acc = wave_sum(acc);
    if (lane == 0) logits[v] = acc + b_out[v];
}

// ---------------------------------------------------------------------------
// 5. per-block online log-sum-exp partials over logits. grid=128, block=256.
__global__ void lse_partial_kernel(const float* __restrict__ logits,
                                   float* __restrict__ pm,
                                   float* __restrict__ ps) {
    __shared__ float rm[4], rs[4];
    int tid = blockIdx.x * 256 + threadIdx.x;
    float m = -1e30f, s = 0.f;
    for (int v = tid; v < VOCAB; v += 128 * 256) lse_combine(m, s, logits[v], 1.f);
    int lane = threadIdx.x & 63, wave = threadIdx.x >> 6;
#pragma unroll
    for (int off = 32; off; off >>= 1) {
        float m2 = __shfl_down(m, off, 64);
        float s2 = __shfl_down(s, off, 64);
        lse_combine(m, s, m2, s2);
    }
    if (lane == 0) { rm[wave] = m; rs[wave] = s; }
    __syncthreads();
    if (threadIdx.x == 0) {
        float fm = rm[0], fs = rs[0];
        for (int w = 1; w < 4; ++w) lse_combine(fm, fs, rm[w], rs[w]);
        pm[blockIdx.x] = fm;
        ps[blockIdx.x] = fs;
    }
}

// ---------------------------------------------------------------------------
// 6. out[v] = logits[v] - M, M recomputed per block from 128 partials.
__global__ void out_kernel(const float* __restrict__ logits,
                           const float* __restrict__ pm,
                           const float* __restrict__ ps,
                           float* __restrict__ out) {
    __shared__ float rm[2], rs[2], Msh;
    int t = threadIdx.x, lane = t & 63, wave = t >> 6;
    float m = -1e30f, s = 0.f;
    if (t < 128) { m = pm[t]; s = ps[t]; }
#pragma unroll
    for (int off = 32; off; off >>= 1) {
        float m2 = __shfl_down(m, off, 64);
        float s2 = __shfl_down(s, off, 64);
        lse_combine(m, s, m2, s2);
    }
    if (lane == 0 && wave < 2) { rm[wave] = m; rs[wave] = s; }
    __syncthreads();
    if (t == 0) {
        float fm = rm[0], fs = rs[0];
        lse_combine(fm, fs, rm[1], rs[1]);
        Msh = fm + logf(fs);
    }
    __syncthreads();
    float M = Msh;
    int v = blockIdx.x * 256 + t;
    if (v < VOCAB) out[v] = logits[v] - M;
}

// ---------------------------------------------------------------------------
extern "C" void kernel_launch(void* const* d_in, const int* in_sizes, int n_in,
                              void* d_out, int out_size, void* d_ws, size_t ws_size,
                              hipStream_t stream) {
    const int*   tok    = (const int*)d_in[0];
    const float* hidden = (const float*)d_in[1];
    const float* enc    = (const float*)d_in[2];
    const float* emb    = (const float*)d_in[3];
    const float* W_ih   = (const float*)d_in[4];
    const float* W_hh   = (const float*)d_in[5];
    const float* b_ih   = (const float*)d_in[6];
    const float* b_hh   = (const float*)d_in[7];
    const float* W_out  = (const float*)d_in[8];
    const float* b_out  = (const float*)d_in[9];
    float* out = (float*)d_out;

    float* ws     = (float*)d_ws;
    float* concat = ws;                  // 4096
    float* pm_a   = ws + 4096;           // 128
    float* ps_a   = ws + 4224;           // 128
    float* pm     = ws + 4352;           // 128
    float* ps     = ws + 4480;           // 128
    float* part   = ws + 4608;           // 128*1024 = 131072
    float* logits = ws + 4608;           // aliases part (dead before K4)
    // footprint: 4608 + 131072 = 135680 floats ≈ 543 KB (< proven 642 KB)

    rnn_kernel<<<512, 256, 0, stream>>>(tok, hidden, emb, W_ih, W_hh, b_ih, b_hh,
                                        concat, out + VOCAB);
    flash_attn_kernel<<<128, 256, 0, stream>>>(enc, concat, part, pm_a, ps_a);
    attn_combine_kernel<<<8, 256, 0, stream>>>(part, pm_a, ps_a, concat);
    logits_kernel<<<(VOCAB + 3) / 4, 256, 0, stream>>>(W_out, b_out, concat, logits);
    lse_partial_kernel<<<128, 256, 0, stream>>>(logits, pm, ps);
    out_kernel<<<(VOCAB + 255) / 256, 256, 0, stream>>>(logits, pm, ps, out);
}